// Round 2
// baseline (132.201 us; speedup 1.0000x reference)
//
#include <hip/hip_runtime.h>
#include <hip/hip_bf16.h>
#include <math.h>

#define A_TOTAL 250000
#define BCNT 8
#define NANN 16

// ws layout (bytes):
//  [0,    2048) : annBox  B*N float4 (x1,y1,x2,y2)  (invalid -> degenerate box)
//  [2048, 2560) : annArea B*N float                 (invalid -> 1e30)
//  [2560, 4608) : annGT   B*N float4 (cx,cy,th,len)
//  [4608, 5120) : annCls  B*N float  (class, -1 if invalid)
//  [5120, 6144) : keys    B*N u64    (iou_bits<<32 | (0xFFFFFFFF - anchor))
//  [6144, 6240) : acc     B*3 float  (cls_sum, reg_sum, npos)

__device__ __forceinline__ float focal_term(float pc, bool is_one) {
    if (is_one) return 0.25f * (1.f - pc) * (1.f - pc) * (-__logf(pc));
    return 0.75f * pc * pc * (-__logf(1.f - pc));
}

__global__ __launch_bounds__(256) void detloss_init(
    const float* __restrict__ ann, float4* __restrict__ annBox,
    float* __restrict__ annArea, float4* __restrict__ annGT,
    float* __restrict__ annCls, unsigned long long* __restrict__ keys,
    float* __restrict__ acc)
{
    int tid = threadIdx.x;
    if (tid < BCNT * NANN) {
        const float* a = ann + tid * 5;
        float cx = a[0], cy = a[1], th = a[2], ln = a[3], cl = a[4];
        bool valid = (cl != -1.0f);
        float dx = fabsf(0.5f * ln * cosf(th));
        float dy = fabsf(0.5f * ln * sinf(th));
        float x1 = cx - dx, y1 = cy - dy, x2 = cx + dx, y2 = cy + dy;
        if (!valid) { x1 = y1 = x2 = y2 = 3.0e8f; }   // degenerate: inter = 0
        annBox[tid] = make_float4(x1, y1, x2, y2);
        annArea[tid] = valid ? (x2 - x1) * (y2 - y1) : 1.0e30f;  // iou -> 0
        annGT[tid] = make_float4(cx, cy, th, ln);
        annCls[tid] = cl;
        keys[tid] = 0ULL;
    }
    if (tid < BCNT * 3) acc[tid] = 0.f;
}

__global__ __launch_bounds__(256) void detloss_main(
    const float* __restrict__ cls, const float* __restrict__ reg,
    const float* __restrict__ anchors,
    const float4* __restrict__ annBox, const float* __restrict__ annArea,
    const float4* __restrict__ annGT, const float* __restrict__ annCls,
    unsigned long long* __restrict__ keys, float* __restrict__ acc)
{
    int b = blockIdx.y;
    int tid = threadIdx.x;

    // ---- wave-uniform ann constants (scalar-promoted, hoisted) ----
    float bx1[NANN], by1[NANN], bx2[NANN], by2[NANN], bar[NANN];
#pragma unroll
    for (int n = 0; n < NANN; n++) {
        float4 t = annBox[b * NANN + n];
        bx1[n] = t.x; by1[n] = t.y; bx2[n] = t.z; by2[n] = t.w;
        bar[n] = annArea[b * NANN + n];
    }
    // gt + class staged to LDS (read only for positive anchors)
    __shared__ float sGT[NANN][5];
    __shared__ unsigned long long sKey[4][NANN];
    __shared__ float sPart[4][3];
    if (tid < NANN) {
        float4 g = annGT[b * NANN + tid];
        sGT[tid][0] = g.x; sGT[tid][1] = g.y; sGT[tid][2] = g.z; sGT[tid][3] = g.w;
        sGT[tid][4] = annCls[b * NANN + tid];
    }
    __syncthreads();

    float bm[NANN]; int bi[NANN];
#pragma unroll
    for (int n = 0; n < NANN; n++) { bm[n] = -1.f; bi[n] = 0; }
    float clsS = 0.f, regS = 0.f, nposS = 0.f;

    const float4* clsB = (const float4*)(cls + (size_t)b * A_TOTAL * 4);
    const float4* regB = (const float4*)(reg + (size_t)b * A_TOTAL * 4);
    const float4* anc4 = (const float4*)anchors;

    for (int a = blockIdx.x * blockDim.x + tid; a < A_TOTAL; a += gridDim.x * blockDim.x) {
        float4 ap = anc4[a];
        float aw = ap.z - ap.x, ah = ap.w - ap.y;
        float aarea = aw * ah;
        float best = -1.f; int barg = 0;
#pragma unroll
        for (int n = 0; n < NANN; n++) {
            float iw = fminf(ap.z, bx2[n]) - fmaxf(ap.x, bx1[n]);
            float ih = fminf(ap.w, by2[n]) - fmaxf(ap.y, by1[n]);
            iw = fmaxf(iw, 0.f); ih = fmaxf(ih, 0.f);
            float inter = iw * ih;
            float ua = fmaxf(aarea + bar[n] - inter, 1e-8f);
            float iou = inter * __builtin_amdgcn_rcpf(ua);
            if (iou > best) { best = iou; barg = n; }
            if (iou > bm[n]) { bm[n] = iou; bi[n] = a; }
        }
        if (best < 0.4f || best >= 0.5f) {
            float4 p4 = clsB[a];
            float p[4] = {p4.x, p4.y, p4.z, p4.w};
            bool pos = (best >= 0.5f);
            int ac = pos ? (int)sGT[barg][4] : -1;
            float fl = 0.f;
#pragma unroll
            for (int c = 0; c < 4; c++) {
                float pc = fminf(fmaxf(p[c], 1e-4f), 1.f - 1e-4f);
                fl += focal_term(pc, c == ac);
            }
            clsS += fl;
            if (pos) {
                nposS += 1.f;
                float4 r = regB[a];
                float cxa = (ap.x + ap.z) * 0.5f, cya = (ap.y + ap.w) * 0.5f;
                float L = sqrtf(aw * aw + ah * ah);
                float th = (ap.x == ap.z) ? copysignf(1.5707963267948966f, ah)
                                          : atanf(ah / aw);
                float pr0 = r.x * aw + cxa;
                float pr1 = r.y * ah + cya;
                float pr2 = r.z + th;
                float pr3 = expf(r.w) * L;
                float s = 0.f, d, ad;
                d = pr0 - sGT[barg][0]; ad = fabsf(d); s += (ad < 1.f) ? 0.5f * d * d : ad - 0.5f;
                d = pr1 - sGT[barg][1]; ad = fabsf(d); s += (ad < 1.f) ? 0.5f * d * d : ad - 0.5f;
                d = pr2 - sGT[barg][2]; ad = fabsf(d); s += (ad < 1.f) ? 0.5f * d * d : ad - 0.5f;
                d = pr3 - sGT[barg][3]; ad = fabsf(d); s += (ad < 1.f) ? 0.5f * d * d : ad - 0.5f;
                regS += s * 0.25f;
            }
        }
    }

    int lane = tid & 63, wv = tid >> 6;
#pragma unroll
    for (int n = 0; n < NANN; n++) {
        unsigned long long k =
            ((unsigned long long)__float_as_uint(fmaxf(bm[n], 0.f)) << 32) |
            (unsigned long long)(0xFFFFFFFFu - (unsigned)bi[n]);
        for (int off = 32; off > 0; off >>= 1) {
            unsigned long long o = __shfl_xor(k, off, 64);
            if (o > k) k = o;
        }
        if (lane == 0) sKey[wv][n] = k;
    }
    for (int off = 32; off > 0; off >>= 1) {
        clsS  += __shfl_xor(clsS, off, 64);
        regS  += __shfl_xor(regS, off, 64);
        nposS += __shfl_xor(nposS, off, 64);
    }
    if (lane == 0) { sPart[wv][0] = clsS; sPart[wv][1] = regS; sPart[wv][2] = nposS; }
    __syncthreads();
    if (tid < NANN) {
        unsigned long long k = sKey[0][tid];
#pragma unroll
        for (int w = 1; w < 4; w++) if (sKey[w][tid] > k) k = sKey[w][tid];
        atomicMax(&keys[b * NANN + tid], k);
    }
    if (tid == 0) {
        float c0 = 0, c1 = 0, c2 = 0;
        for (int w = 0; w < 4; w++) { c0 += sPart[w][0]; c1 += sPart[w][1]; c2 += sPart[w][2]; }
        atomicAdd(&acc[b * 3 + 0], c0);
        atomicAdd(&acc[b * 3 + 1], c1);
        atomicAdd(&acc[b * 3 + 2], c2);
    }
}

__global__ __launch_bounds__(256) void detloss_fin(
    const float* __restrict__ cls, const float* __restrict__ reg,
    const float* __restrict__ anchors,
    const float4* __restrict__ annBox, const float* __restrict__ annArea,
    const float4* __restrict__ annGT, const float* __restrict__ annCls,
    const unsigned long long* __restrict__ keys, const float* __restrict__ acc,
    float* __restrict__ out)
{
    __shared__ int sForce[BCNT][NANN];
    __shared__ float sAcc[BCNT][3];
    int tid = threadIdx.x;
    if (tid < BCNT * 3) sAcc[tid / 3][tid % 3] = acc[tid];
    if (tid < BCNT * NANN) {
        unsigned long long k = keys[tid];
        float amax = __uint_as_float((unsigned)(k >> 32));
        float bcls = annCls[tid];
        bool force = (bcls != -1.f) && (amax < 0.5f) && (k != 0ULL);
        int anchor = (int)(0xFFFFFFFFu - (unsigned)(k & 0xFFFFFFFFu));
        int b = tid / NANN, n = tid % NANN;
        sForce[b][n] = (force && anchor >= 0 && anchor < A_TOTAL) ? anchor : -1;
    }
    __syncthreads();
    if (tid < BCNT) {
        int b = tid;
        const float4* clsB = (const float4*)(cls + (size_t)b * A_TOTAL * 4);
        const float4* regB = (const float4*)(reg + (size_t)b * A_TOTAL * 4);
        const float4* anc4 = (const float4*)anchors;
        float dC = 0.f, dR = 0.f, dN = 0.f;
        for (int n = 0; n < NANN; n++) {
            int idx = sForce[b][n];
            if (idx < 0) continue;
            bool first = true;
            for (int m = 0; m < n; m++) if (sForce[b][m] == idx) first = false;
            if (!first) continue;

            float4 ap = anc4[idx];
            float aw = ap.z - ap.x, ah = ap.w - ap.y;
            float aarea = aw * ah;
            // --- old state (bit-identical recompute of main's path) ---
            float best = -1.f; int barg = 0;
            for (int m = 0; m < NANN; m++) {
                float4 bb = annBox[b * NANN + m];
                float ar = annArea[b * NANN + m];
                float iw = fminf(ap.z, bb.z) - fmaxf(ap.x, bb.x);
                float ih = fminf(ap.w, bb.w) - fmaxf(ap.y, bb.y);
                iw = fmaxf(iw, 0.f); ih = fmaxf(ih, 0.f);
                float inter = iw * ih;
                float ua = fmaxf(aarea + ar - inter, 1e-8f);
                float iou = inter * __builtin_amdgcn_rcpf(ua);
                if (iou > best) { best = iou; barg = m; }
            }
            float4 p4 = clsB[idx];
            float p[4] = {p4.x, p4.y, p4.z, p4.w};
            float cxa = (ap.x + ap.z) * 0.5f, cya = (ap.y + ap.w) * 0.5f;
            float L = sqrtf(aw * aw + ah * ah);
            float th = (ap.x == ap.z) ? copysignf(1.5707963267948966f, ah)
                                      : atanf(ah / aw);
            float oldc = 0.f, oldr = 0.f, oldn = 0.f;
            if (best < 0.4f || best >= 0.5f) {
                bool pos = (best >= 0.5f);
                int ac = pos ? (int)annCls[b * NANN + barg] : -1;
                for (int c = 0; c < 4; c++) {
                    float pc = fminf(fmaxf(p[c], 1e-4f), 1.f - 1e-4f);
                    oldc += focal_term(pc, c == ac);
                }
                if (pos) {
                    oldn = 1.f;
                    float4 r = regB[idx];
                    float4 g = annGT[b * NANN + barg];
                    float pr0 = r.x * aw + cxa;
                    float pr1 = r.y * ah + cya;
                    float pr2 = r.z + th;
                    float pr3 = expf(r.w) * L;
                    float s = 0.f, d, ad;
                    d = pr0 - g.x; ad = fabsf(d); s += (ad < 1.f) ? 0.5f * d * d : ad - 0.5f;
                    d = pr1 - g.y; ad = fabsf(d); s += (ad < 1.f) ? 0.5f * d * d : ad - 0.5f;
                    d = pr2 - g.z; ad = fabsf(d); s += (ad < 1.f) ? 0.5f * d * d : ad - 0.5f;
                    d = pr3 - g.w; ad = fabsf(d); s += (ad < 1.f) ? 0.5f * d * d : ad - 0.5f;
                    oldr = s * 0.25f;
                }
            }
            // --- new state: union of onehots of forced anns hitting idx ---
            unsigned cmask = 0; int lastm = n;
            for (int m = 0; m < NANN; m++)
                if (sForce[b][m] == idx) { cmask |= 1u << (int)annCls[b * NANN + m]; lastm = m; }
            float newc = 0.f;
            for (int c = 0; c < 4; c++) {
                float pc = fminf(fmaxf(p[c], 1e-4f), 1.f - 1e-4f);
                newc += focal_term(pc, (cmask >> c) & 1);
            }
            float4 r = regB[idx];
            float4 g = annGT[b * NANN + lastm];
            float pr0 = r.x * aw + cxa;
            float pr1 = r.y * ah + cya;
            float pr2 = r.z + th;
            float pr3 = expf(r.w) * L;
            float s = 0.f, d, ad;
            d = pr0 - g.x; ad = fabsf(d); s += (ad < 1.f) ? 0.5f * d * d : ad - 0.5f;
            d = pr1 - g.y; ad = fabsf(d); s += (ad < 1.f) ? 0.5f * d * d : ad - 0.5f;
            d = pr2 - g.z; ad = fabsf(d); s += (ad < 1.f) ? 0.5f * d * d : ad - 0.5f;
            d = pr3 - g.w; ad = fabsf(d); s += (ad < 1.f) ? 0.5f * d * d : ad - 0.5f;
            float newr = s * 0.25f;

            dC += newc - oldc;
            dR += newr - oldr;
            dN += 1.f - oldn;
        }
        sAcc[b][0] += dC; sAcc[b][1] += dR; sAcc[b][2] += dN;
    }
    __syncthreads();
    if (tid == 0) {
        float cm = 0.f, rm = 0.f;
        for (int b = 0; b < BCNT; b++) {
            float np = fmaxf(sAcc[b][2], 1.f);
            cm += sAcc[b][0] / np;
            rm += sAcc[b][1] / np;
        }
        out[0] = cm * 0.125f;
        out[1] = rm * 0.125f;
    }
}

extern "C" void kernel_launch(void* const* d_in, const int* in_sizes, int n_in,
                              void* d_out, int out_size, void* d_ws, size_t ws_size,
                              hipStream_t stream) {
    const float* classifications = (const float*)d_in[0];
    const float* regressions     = (const float*)d_in[1];
    const float* anchors_pos     = (const float*)d_in[2];
    const float* annotations     = (const float*)d_in[3];
    float* out = (float*)d_out;

    char* ws = (char*)d_ws;
    float4* annBox = (float4*)(ws + 0);
    float*  annArea = (float*)(ws + 2048);
    float4* annGT  = (float4*)(ws + 2560);
    float*  annCls = (float*)(ws + 4608);
    unsigned long long* keys = (unsigned long long*)(ws + 5120);
    float*  acc = (float*)(ws + 6144);

    detloss_init<<<1, 256, 0, stream>>>(annotations, annBox, annArea, annGT, annCls, keys, acc);
    detloss_main<<<dim3(256, BCNT), 256, 0, stream>>>(
        classifications, regressions, anchors_pos, annBox, annArea, annGT, annCls, keys, acc);
    detloss_fin<<<1, 256, 0, stream>>>(
        classifications, regressions, anchors_pos, annBox, annArea, annGT, annCls, keys, acc, out);
}

// Round 3
// 66.831 us; speedup vs baseline: 1.9781x; 1.9781x over previous
//
#include <hip/hip_runtime.h>
#include <math.h>

#define A_TOTAL 250000
#define BCNT 8
#define NANN 16
#define GX 96
#define NBLK (GX * BCNT)
#define NTHR 256
#define STRIDE (GX * NTHR)

// ws layout (bytes): [0,1024) keys B*N u64 ; [1024,1120) acc B*3 f32 ; [1120,1124) counter u32
// all zeroed by hipMemsetAsync each call.

__device__ __forceinline__ void ann_consts(const float* a5,
    float& x1, float& y1, float& x2, float& y2, float& area)
{
    float cx = a5[0], cy = a5[1], th = a5[2], ln = a5[3], cl = a5[4];
    bool valid = (cl != -1.0f);
    float dx = fabsf(0.5f * ln * cosf(th));
    float dy = fabsf(0.5f * ln * sinf(th));
    x1 = cx - dx; y1 = cy - dy; x2 = cx + dx; y2 = cy + dy;
    area = (x2 - x1) * (y2 - y1);
    if (!valid) { x1 = y1 = x2 = y2 = 3.0e8f; area = 1.0e30f; }
}

__device__ __forceinline__ float4 pred_cal(float4 ap, float4 r, float aw, float ah) {
    float cxa = (ap.x + ap.z) * 0.5f, cya = (ap.y + ap.w) * 0.5f;
    float L = sqrtf(aw * aw + ah * ah);
    float th = (ap.x == ap.z) ? copysignf(1.5707963267948966f, ah) : atanf(ah / aw);
    return make_float4(r.x * aw + cxa, r.y * ah + cya, r.z + th, expf(r.w) * L);
}

__device__ __forceinline__ float sl1(float4 pr, float4 g) {
    float s = 0.f, d, ad;
    d = pr.x - g.x; ad = fabsf(d); s += (ad < 1.f) ? 0.5f * d * d : ad - 0.5f;
    d = pr.y - g.y; ad = fabsf(d); s += (ad < 1.f) ? 0.5f * d * d : ad - 0.5f;
    d = pr.z - g.z; ad = fabsf(d); s += (ad < 1.f) ? 0.5f * d * d : ad - 0.5f;
    d = pr.w - g.w; ad = fabsf(d); s += (ad < 1.f) ? 0.5f * d * d : ad - 0.5f;
    return s * 0.25f;
}

// mask-based focal (finalize path only)
__device__ __forceinline__ float focal4m(float4 p4, unsigned mask) {
    float pv[4] = {p4.x, p4.y, p4.z, p4.w};
    float fl = 0.f;
#pragma unroll
    for (int c = 0; c < 4; c++) {
        float pc = fminf(fmaxf(pv[c], 1e-4f), 1.f - 1e-4f);
        fl += ((mask >> c) & 1) ? 0.25f * (1.f - pc) * (1.f - pc) * (-__logf(pc))
                                : 0.75f * pc * pc * (-__logf(1.f - pc));
    }
    return fl;
}

__global__ __launch_bounds__(NTHR, 3) void detloss_fused(
    const float* __restrict__ cls, const float* __restrict__ reg,
    const float* __restrict__ anchors, const float* __restrict__ ann,
    unsigned long long* __restrict__ keys, float* __restrict__ acc,
    unsigned* __restrict__ counter, float* __restrict__ out)
{
    int b = blockIdx.y;
    int tid = threadIdx.x;
    __shared__ float sBox[NANN][5];                 // x1,y1,x2,y2,area
    __shared__ float sGT[NANN][5];                  // cx,cy,th,len,cls
    __shared__ unsigned long long sK[NTHR][NANN + 1];
    __shared__ float sPart[4][3];
    __shared__ int sLast;

    if (tid < NANN) {
        const float* a5 = ann + (b * NANN + tid) * 5;
        float x1, y1, x2, y2, ar;
        ann_consts(a5, x1, y1, x2, y2, ar);
        sBox[tid][0] = x1; sBox[tid][1] = y1; sBox[tid][2] = x2; sBox[tid][3] = y2; sBox[tid][4] = ar;
        sGT[tid][0] = a5[0]; sGT[tid][1] = a5[1]; sGT[tid][2] = a5[2]; sGT[tid][3] = a5[3]; sGT[tid][4] = a5[4];
    }
    __syncthreads();

    // ann constants -> registers (one-time LDS reads, fully unrolled -> SSA scalars)
    float bx1[NANN], by1[NANN], bx2[NANN], by2[NANN], bar[NANN];
#pragma unroll
    for (int n = 0; n < NANN; n++) {
        bx1[n] = sBox[n][0]; by1[n] = sBox[n][1];
        bx2[n] = sBox[n][2]; by2[n] = sBox[n][3]; bar[n] = sBox[n][4];
    }
    float bm[NANN]; int bi[NANN];
#pragma unroll
    for (int n = 0; n < NANN; n++) { bm[n] = -1.f; bi[n] = 0; }
    float clsS = 0.f, regS = 0.f, nposS = 0.f;

    const float4* clsB = (const float4*)(cls + (size_t)b * A_TOTAL * 4);
    const float4* regB = (const float4*)(reg + (size_t)b * A_TOTAL * 4);
    const float4* anc4 = (const float4*)anchors;

    int a = blockIdx.x * NTHR + tid;
    float4 ap = anc4[a];
    while (a < A_TOTAL) {
        float4 p4 = clsB[a];                       // issued early, used late
        int a2 = a + STRIDE;
        int apre = (a2 < A_TOTAL) ? a2 : a;
        float4 apn = anc4[apre];                   // prefetch next anchor

        float aw = ap.z - ap.x, ah = ap.w - ap.y;
        float aarea = aw * ah;
        float best = -1.f; int barg = 0;
#pragma unroll
        for (int n = 0; n < NANN; n++) {
            float iw = fminf(ap.z, bx2[n]) - fmaxf(ap.x, bx1[n]);
            float ih = fminf(ap.w, by2[n]) - fmaxf(ap.y, by1[n]);
            iw = fmaxf(iw, 0.f); ih = fmaxf(ih, 0.f);
            float inter = iw * ih;
            float ua = fmaxf(aarea + bar[n] - inter, 1e-8f);
            float iou = inter * __builtin_amdgcn_rcpf(ua);
            if (iou > best) { best = iou; barg = n; }
            if (iou > bm[n]) { bm[n] = iou; bi[n] = a; }
        }
        if (best < 0.4f || best >= 0.5f) {
            bool pos = (best >= 0.5f);
            // neg-branch focal for all 4 classes; correct the positive class if pos (rare)
            float pc0 = fminf(fmaxf(p4.x, 1e-4f), 1.f - 1e-4f);
            float pc1 = fminf(fmaxf(p4.y, 1e-4f), 1.f - 1e-4f);
            float pc2 = fminf(fmaxf(p4.z, 1e-4f), 1.f - 1e-4f);
            float pc3 = fminf(fmaxf(p4.w, 1e-4f), 1.f - 1e-4f);
            float fl = 0.75f * pc0 * pc0 * (-__logf(1.f - pc0))
                     + 0.75f * pc1 * pc1 * (-__logf(1.f - pc1))
                     + 0.75f * pc2 * pc2 * (-__logf(1.f - pc2))
                     + 0.75f * pc3 * pc3 * (-__logf(1.f - pc3));
            if (pos) {
                int ac = (int)sGT[barg][4];
                float pc = ac == 0 ? pc0 : ac == 1 ? pc1 : ac == 2 ? pc2 : pc3;
                fl += 0.25f * (1.f - pc) * (1.f - pc) * (-__logf(pc))
                    - 0.75f * pc * pc * (-__logf(1.f - pc));
                nposS += 1.f;
                float4 r = regB[a];
                float4 pr = pred_cal(ap, r, aw, ah);
                float4 g = make_float4(sGT[barg][0], sGT[barg][1], sGT[barg][2], sGT[barg][3]);
                regS += sl1(pr, g);
            }
            clsS += fl;
        }
        ap = apn; a = a2;
    }

    // ---- per-ann key reduction: LDS transpose ----
#pragma unroll
    for (int n = 0; n < NANN; n++) {
        sK[tid][n] = ((unsigned long long)__float_as_uint(fmaxf(bm[n], 0.f)) << 32)
                   | (unsigned long long)(0xFFFFFFFFu - (unsigned)bi[n]);
    }
    // ---- float sums: wave shfl ----
    int lane = tid & 63, wv = tid >> 6;
#pragma unroll
    for (int off = 1; off < 64; off <<= 1) {
        clsS  += __shfl_xor(clsS, off, 64);
        regS  += __shfl_xor(regS, off, 64);
        nposS += __shfl_xor(nposS, off, 64);
    }
    if (lane == 0) { sPart[wv][0] = clsS; sPart[wv][1] = regS; sPart[wv][2] = nposS; }
    __syncthreads();
    {
        int n = tid >> 4, j = tid & 15;            // 256 threads cover 16 anns x 16 groups
        unsigned long long m = 0ULL;
#pragma unroll
        for (int i = 0; i < 16; i++) {
            unsigned long long v = sK[i * 16 + j][n];
            if (v > m) m = v;
        }
#pragma unroll
        for (int off = 1; off < 16; off <<= 1) {   // within 16-lane group (same wave)
            unsigned long long o = __shfl_xor(m, off, 64);
            if (o > m) m = o;
        }
        if (j == 0) atomicMax(&keys[b * NANN + n], m);
    }
    if (tid == 0) {
        float c0 = 0, c1 = 0, c2 = 0;
        for (int w = 0; w < 4; w++) { c0 += sPart[w][0]; c1 += sPart[w][1]; c2 += sPart[w][2]; }
        atomicAdd(&acc[b * 3 + 0], c0);
        atomicAdd(&acc[b * 3 + 1], c1);
        atomicAdd(&acc[b * 3 + 2], c2);
        __threadfence();
        unsigned c = atomicAdd(counter, 1u);
        sLast = (c == NBLK - 1) ? 1 : 0;
    }
    __syncthreads();
    if (!sLast) return;

    // ================= finalize (exactly one block reaches here) =================
    __shared__ float fBox[BCNT][NANN][5];
    __shared__ float fGT[BCNT][NANN][5];
    __shared__ int   fForce[BCNT][NANN];
    __shared__ float fAcc[BCNT][3];

    if (tid < BCNT * NANN) {
        int fb = tid >> 4, fn = tid & 15;
        const float* a5 = ann + (fb * NANN + fn) * 5;
        float x1, y1, x2, y2, ar;
        ann_consts(a5, x1, y1, x2, y2, ar);
        fBox[fb][fn][0] = x1; fBox[fb][fn][1] = y1; fBox[fb][fn][2] = x2; fBox[fb][fn][3] = y2; fBox[fb][fn][4] = ar;
        fGT[fb][fn][0] = a5[0]; fGT[fb][fn][1] = a5[1]; fGT[fb][fn][2] = a5[2]; fGT[fb][fn][3] = a5[3]; fGT[fb][fn][4] = a5[4];
    }
    if (tid < BCNT * 3) fAcc[tid / 3][tid % 3] = atomicAdd(&acc[tid], 0.0f);   // coherent read
    __syncthreads();
    if (tid < BCNT * NANN) {
        int fb = tid >> 4, fn = tid & 15;
        unsigned long long k = atomicMax(&keys[tid], 0ULL);                     // coherent read
        float amax = __uint_as_float((unsigned)(k >> 32));
        float cl = fGT[fb][fn][4];
        bool force = (cl != -1.f) && (amax < 0.5f) && (k != 0ULL);
        int anchor = (int)(0xFFFFFFFFu - (unsigned)(k & 0xFFFFFFFFu));
        fForce[fb][fn] = (force && anchor >= 0 && anchor < A_TOTAL) ? anchor : -1;
    }
    __syncthreads();
    if (tid < BCNT * NANN) {
        int fb = tid >> 4, fn = tid & 15;
        int idx = fForce[fb][fn];
        bool first = (idx >= 0);
        for (int m = 0; m < fn; m++) if (fForce[fb][m] == idx) first = false;
        if (idx >= 0 && first) {
            const float4* clsBf = (const float4*)(cls + (size_t)fb * A_TOTAL * 4);
            const float4* regBf = (const float4*)(reg + (size_t)fb * A_TOTAL * 4);
            float4 ap2 = ((const float4*)anchors)[idx];
            float aw = ap2.z - ap2.x, ah = ap2.w - ap2.y;
            float aarea = aw * ah;
            // old state: bit-identical recompute of main's inner loop
            float best = -1.f; int barg = 0;
#pragma unroll
            for (int m = 0; m < NANN; m++) {
                float iw = fminf(ap2.z, fBox[fb][m][2]) - fmaxf(ap2.x, fBox[fb][m][0]);
                float ih = fminf(ap2.w, fBox[fb][m][3]) - fmaxf(ap2.y, fBox[fb][m][1]);
                iw = fmaxf(iw, 0.f); ih = fmaxf(ih, 0.f);
                float inter = iw * ih;
                float ua = fmaxf(aarea + fBox[fb][m][4] - inter, 1e-8f);
                float iou = inter * __builtin_amdgcn_rcpf(ua);
                if (iou > best) { best = iou; barg = m; }
            }
            float4 p4 = clsBf[idx];
            float oldc = 0.f, oldr = 0.f, oldn = 0.f;
            if (best < 0.4f || best >= 0.5f) {
                bool pos = (best >= 0.5f);
                unsigned msk = pos ? (1u << (int)fGT[fb][barg][4]) : 0u;
                oldc = focal4m(p4, msk);
                if (pos) {
                    oldn = 1.f;
                    float4 r = regBf[idx];
                    float4 pr = pred_cal(ap2, r, aw, ah);
                    float4 g = make_float4(fGT[fb][barg][0], fGT[fb][barg][1], fGT[fb][barg][2], fGT[fb][barg][3]);
                    oldr = sl1(pr, g);
                }
            }
            // new state: union of onehots of all forced anns hitting idx; gt = last writer
            unsigned cmask = 0; int lastm = fn;
            for (int m = 0; m < NANN; m++)
                if (fForce[fb][m] == idx) { cmask |= 1u << (int)fGT[fb][m][4]; lastm = m; }
            float newc = focal4m(p4, cmask);
            float4 r = regBf[idx];
            float4 pr = pred_cal(ap2, r, aw, ah);
            float4 g = make_float4(fGT[fb][lastm][0], fGT[fb][lastm][1], fGT[fb][lastm][2], fGT[fb][lastm][3]);
            float newr = sl1(pr, g);
            atomicAdd(&fAcc[fb][0], newc - oldc);
            atomicAdd(&fAcc[fb][1], newr - oldr);
            atomicAdd(&fAcc[fb][2], 1.f - oldn);
        }
    }
    __syncthreads();
    if (tid == 0) {
        float cm = 0.f, rm = 0.f;
        for (int fb = 0; fb < BCNT; fb++) {
            float np = fmaxf(fAcc[fb][2], 1.f);
            cm += fAcc[fb][0] / np;
            rm += fAcc[fb][1] / np;
        }
        out[0] = cm * 0.125f;
        out[1] = rm * 0.125f;
    }
}

extern "C" void kernel_launch(void* const* d_in, const int* in_sizes, int n_in,
                              void* d_out, int out_size, void* d_ws, size_t ws_size,
                              hipStream_t stream) {
    const float* classifications = (const float*)d_in[0];
    const float* regressions     = (const float*)d_in[1];
    const float* anchors_pos     = (const float*)d_in[2];
    const float* annotations     = (const float*)d_in[3];
    float* out = (float*)d_out;

    char* ws = (char*)d_ws;
    unsigned long long* keys = (unsigned long long*)(ws + 0);      // 1024 B
    float* acc = (float*)(ws + 1024);                              // 96 B
    unsigned* counter = (unsigned*)(ws + 1120);                    // 4 B

    hipMemsetAsync(ws, 0, 1152, stream);
    detloss_fused<<<dim3(GX, BCNT), NTHR, 0, stream>>>(
        classifications, regressions, anchors_pos, annotations,
        keys, acc, counter, out);
}